// Round 5
// baseline (4135.250 us; speedup 1.0000x reference)
//
#include <hip/hip_runtime.h>

#define BB 4
#define HH 20
#define DHD 64
#define DD 1280
#define DFFN 5120
#define VV 8000
#define HIST 1024
#define TENC 512
#define KVLEN 1025
#define NLAYER 16

// ---------------- output offsets (floats) ----------------
static const size_t NK_OFF = 0;
static const size_t NV_OFF = 83968000ull;              // 16*4*20*64*1025
static const size_t LG_OFF = 167936000ull;
static const size_t KV_IDX = 167968000ull;

__device__ __forceinline__ void fma4(float4& a, float s, const float4& w) {
    a.x += s * w.x; a.y += s * w.y; a.z += s * w.z; a.w += s * w.w;
}

// ---------------- embed ----------------
__global__ __launch_bounds__(256) void embed_kernel(
    const float* __restrict__ emb, const float* __restrict__ pe,
    const int* __restrict__ ids, float* __restrict__ x) {
    int i = blockIdx.x * 256 + threadIdx.x;   // B*D = 5120
    if (i >= BB * DD) return;
    int b = i / DD, d = i % DD;
    int tok = ids[b];
    x[i] = emb[(size_t)tok * DD + d] + pe[(size_t)HIST * DD + d];
}

// ---------------- fused residual+LN preload (per-block, redundant) ----------------
// wave w handles batch b=w; lane's elements d = e*64+lane (coalesced).
// v = xold[b][d] + rbias[d] + sum_j pin[j][b][d]; optional write of v to xnew;
// vbuf[b][d] = LN(v).
__device__ __forceinline__ void ln_preload(
    const float* __restrict__ xold, const float* __restrict__ rbias,
    const float* __restrict__ pin, int np,
    const float* __restrict__ lw, const float* __restrict__ lb,
    float* __restrict__ xnew, bool doWrite, float (*vbuf)[DD]) {
    int tid = threadIdx.x;
    int w = tid >> 6, lane = tid & 63;
    float vloc[20];
    float s = 0.f;
#pragma unroll
    for (int e = 0; e < 20; ++e) {
        int d = e * 64 + lane;
        float v = xold[w * DD + d];
        if (rbias) v += rbias[d];
        for (int j = 0; j < np; ++j) v += pin[(size_t)(j * BB + w) * DD + d];
        vloc[e] = v; s += v;
    }
    if (doWrite) {
#pragma unroll
        for (int e = 0; e < 20; ++e) xnew[w * DD + e * 64 + lane] = vloc[e];
    }
#pragma unroll
    for (int off = 32; off; off >>= 1) s += __shfl_xor(s, off, 64);
    float mean = s * (1.0f / DD);
    float sq = 0.f;
#pragma unroll
    for (int e = 0; e < 20; ++e) { float d0 = vloc[e] - mean; sq += d0 * d0; }
#pragma unroll
    for (int off = 32; off; off >>= 1) sq += __shfl_xor(sq, off, 64);
    float rstd = rsqrtf(sq * (1.0f / DD) + 1e-5f);
#pragma unroll
    for (int e = 0; e < 20; ++e) {
        int d = e * 64 + lane;
        vbuf[w][d] = (vloc[e] - mean) * rstd * lw[d] + lb[d];
    }
}

// ---------------- QKV GEMV with fused LN preload ----------------
// grid=(HH, nmat*4), block=256. out: [(mat*4+rc)][h][b][64]
__global__ __launch_bounds__(256) void qkv64(
    const float* __restrict__ w0, const float* __restrict__ w1p, const float* __restrict__ w2p,
    const float* __restrict__ xold, const float* __restrict__ rbias,
    const float* __restrict__ pin, int np,
    const float* __restrict__ lw, const float* __restrict__ lb,
    float* __restrict__ xnew, float* __restrict__ outp) {
    int h = blockIdx.x, my = blockIdx.y;
    int mat = my >> 2, rc = my & 3;
    const float* W = (mat == 0 ? w0 : mat == 1 ? w1p : w2p) + (size_t)h * DD * DHD;
    __shared__ float vbuf[BB][DD];
    __shared__ float red[16][BB][64];
    ln_preload(xold, rbias, pin, np, lw, lb, xnew, (xnew != nullptr) && h == 0 && my == 0, vbuf);
    __syncthreads();
    int tid = threadIdx.x, cl = tid & 15, sg = tid >> 4;
    int row0 = rc * 320;
    float4 a0 = {0,0,0,0}, a1 = {0,0,0,0}, a2 = {0,0,0,0}, a3 = {0,0,0,0};
    const float* Wp = W + (size_t)row0 * DHD + cl * 4;
#pragma unroll 5
    for (int it = 0; it < 20; ++it) {
        int r = sg + it * 16;
        float4 w4 = *(const float4*)(Wp + (size_t)r * DHD);
        int ai = row0 + r;
        fma4(a0, vbuf[0][ai], w4); fma4(a1, vbuf[1][ai], w4);
        fma4(a2, vbuf[2][ai], w4); fma4(a3, vbuf[3][ai], w4);
    }
    int cq = cl * 4;
    red[sg][0][cq+0]=a0.x; red[sg][0][cq+1]=a0.y; red[sg][0][cq+2]=a0.z; red[sg][0][cq+3]=a0.w;
    red[sg][1][cq+0]=a1.x; red[sg][1][cq+1]=a1.y; red[sg][1][cq+2]=a1.z; red[sg][1][cq+3]=a1.w;
    red[sg][2][cq+0]=a2.x; red[sg][2][cq+1]=a2.y; red[sg][2][cq+2]=a2.z; red[sg][2][cq+3]=a2.w;
    red[sg][3][cq+0]=a3.x; red[sg][3][cq+1]=a3.y; red[sg][3][cq+2]=a3.z; red[sg][3][cq+3]=a3.w;
    __syncthreads();
    int b = tid >> 6, c = tid & 63;
    float v = 0.f;
#pragma unroll
    for (int g = 0; g < 16; ++g) v += red[g][b][c];
    outp[(size_t)((my * HH + h) * BB + b) * 64 + c] = v;
}

// ---------------- self-attention chunk (128 positions) + fused cache copy ----------------
// grid=(HH,BB,8) block=256. stats[(b*H+h)*8+c]*66 = {m, sumexp, pv[64]}
__global__ __launch_bounds__(256) void attn_self_A(
    const float* __restrict__ kc, const float* __restrict__ vc,
    const float* __restrict__ qkvp, const float* __restrict__ bq_l,
    const float* __restrict__ bv_l, const float* __restrict__ mflagp,
    float* __restrict__ nk, float* __restrict__ nv, float* __restrict__ stats) {
    int h = blockIdx.x, b = blockIdx.y, c = blockIdx.z;
    int tid = threadIdx.x;
    __shared__ float qs[64], knS[64], vnS[64];
    __shared__ float sc8[8][128];
    __shared__ float parr[128];
    __shared__ float red[128];
    __shared__ float pvred[16][64];
    __shared__ float snS;
    float flag = mflagp[0];
    if (tid < 64) {
        float qv = bq_l[h * 64 + tid];
#pragma unroll
        for (int rc = 0; rc < 4; ++rc) qv += qkvp[(size_t)((rc * HH + h) * BB + b) * 64 + tid];
        qs[tid] = qv;
    } else if (tid < 128) {
        int l2 = tid - 64;
        float kn = 0.f;
#pragma unroll
        for (int rc = 0; rc < 4; ++rc) kn += qkvp[(size_t)(((4 + rc) * HH + h) * BB + b) * 64 + l2];
        knS[l2] = kn;
        if (c == 0) nk[((size_t)(b * HH + h) * 64 + l2) * KVLEN + HIST] = kn;
    } else if (tid < 192) {
        int l2 = tid - 128;
        float vn = bv_l[h * 64 + l2];
#pragma unroll
        for (int rc = 0; rc < 4; ++rc) vn += qkvp[(size_t)(((8 + rc) * HH + h) * BB + b) * 64 + l2];
        vnS[l2] = vn;
        if (c == 0) nv[(size_t)(b * HH + h) * KVLEN * 64 + (size_t)HIST * 64 + l2] = vn;
    }
    __syncthreads();
    // K phase: 64 dh rows x 128 cols (float4), fused copy
    int clK = tid & 31, gK = tid >> 5;
    int jb = c * 128 + clK * 4;
    const float* kb = kc + (size_t)(b * HH + h) * 64 * HIST;
    float* nkb = nk + (size_t)(b * HH + h) * 64 * KVLEN;
    float ax = 0, ay = 0, az = 0, aw = 0;
#pragma unroll
    for (int it = 0; it < 8; ++it) {
        int dh = gK * 8 + it;
        float4 k4 = *(const float4*)(kb + (size_t)dh * HIST + jb);
        float* nr = nkb + (size_t)dh * KVLEN + jb;
        nr[0] = k4.x; nr[1] = k4.y; nr[2] = k4.z; nr[3] = k4.w;
        float qd = qs[dh];
        ax += qd * k4.x; ay += qd * k4.y; az += qd * k4.z; aw += qd * k4.w;
    }
    sc8[gK][clK*4+0] = ax; sc8[gK][clK*4+1] = ay; sc8[gK][clK*4+2] = az; sc8[gK][clK*4+3] = aw;
    __syncthreads();
    float s = 0.f;
    if (tid < 128) {
#pragma unroll
        for (int g = 0; g < 8; ++g) s += sc8[g][tid];
        int j = c * 128 + tid;
        if (j != 0) s += -128.0f * flag;
    }
    if (c == 0 && tid < 64) {       // new-token score (j=1024, masked position)
        float pp = qs[tid] * knS[tid];
#pragma unroll
        for (int off = 32; off; off >>= 1) pp += __shfl_xor(pp, off, 64);
        if (tid == 0) snS = pp + (-128.0f * flag);
    }
    if (tid < 128) red[tid] = s;
    __syncthreads();
    for (int st = 64; st; st >>= 1) { if (tid < st) red[tid] = fmaxf(red[tid], red[tid + st]); __syncthreads(); }
    float m = red[0];
    if (c == 0) m = fmaxf(m, snS);
    __syncthreads();
    float p = 0.f;
    if (tid < 128) { p = expf(s - m); parr[tid] = p; red[tid] = p; }
    __syncthreads();
    for (int st = 64; st; st >>= 1) { if (tid < st) red[tid] += red[tid + st]; __syncthreads(); }
    float ssum = red[0];
    float en = (c == 0) ? expf(snS - m) : 0.0f;
    // V phase: 128 rows x 64 dh (float4), fused copy
    int clV = tid & 15, rg = tid >> 4;
    const float* vb = vc + (size_t)(b * HH + h) * HIST * 64;
    float* nvb = nv + (size_t)(b * HH + h) * KVLEN * 64;
    float vx = 0, vy = 0, vz = 0, vw = 0;
#pragma unroll
    for (int it = 0; it < 8; ++it) {
        int i = rg * 8 + it;
        size_t jj = (size_t)(c * 128 + i);
        float4 v4 = *(const float4*)(vb + jj * 64 + clV * 4);
        *(float4*)(nvb + jj * 64 + clV * 4) = v4;
        float pw = parr[i];
        vx += pw * v4.x; vy += pw * v4.y; vz += pw * v4.z; vw += pw * v4.w;
    }
    pvred[rg][clV*4+0] = vx; pvred[rg][clV*4+1] = vy; pvred[rg][clV*4+2] = vz; pvred[rg][clV*4+3] = vw;
    __syncthreads();
    float* st_ = stats + (size_t)((b * HH + h) * 8 + c) * 66;
    if (tid == 0) { st_[0] = m; st_[1] = ssum + en; }
    if (tid < 64) {
        float pv = 0.f;
#pragma unroll
        for (int rgi = 0; rgi < 16; ++rgi) pv += pvred[rgi][tid];
        if (c == 0) pv += en * vnS[tid];
        st_[2 + tid] = pv;
    }
}

// ---------------- cross-attention chunk (128 positions) ----------------
// grid=(HH,BB,4) block=256. stats[(b*H+h)*4+c]*66
__global__ __launch_bounds__(256) void attn_cross_A(
    const float* __restrict__ ck, const float* __restrict__ cv,
    const float* __restrict__ qkvp, const float* __restrict__ cbq_l,
    float* __restrict__ stats) {
    int h = blockIdx.x, b = blockIdx.y, c = blockIdx.z;
    int tid = threadIdx.x;
    __shared__ float qs[64];
    __shared__ float sc8[8][128];
    __shared__ float parr[128];
    __shared__ float red[128];
    __shared__ float pvred[16][64];
    if (tid < 64) {
        float qv = cbq_l[h * 64 + tid];
#pragma unroll
        for (int rc = 0; rc < 4; ++rc) qv += qkvp[(size_t)((rc * HH + h) * BB + b) * 64 + tid];
        qs[tid] = qv;
    }
    __syncthreads();
    int clK = tid & 31, gK = tid >> 5;
    int jb = c * 128 + clK * 4;
    const float* kb = ck + (size_t)(b * HH + h) * 64 * TENC;
    float ax = 0, ay = 0, az = 0, aw = 0;
#pragma unroll
    for (int it = 0; it < 8; ++it) {
        int dh = gK * 8 + it;
        float4 k4 = *(const float4*)(kb + (size_t)dh * TENC + jb);
        float qd = qs[dh];
        ax += qd * k4.x; ay += qd * k4.y; az += qd * k4.z; aw += qd * k4.w;
    }
    sc8[gK][clK*4+0] = ax; sc8[gK][clK*4+1] = ay; sc8[gK][clK*4+2] = az; sc8[gK][clK*4+3] = aw;
    __syncthreads();
    float s = 0.f;
    if (tid < 128) {
#pragma unroll
        for (int g = 0; g < 8; ++g) s += sc8[g][tid];
    }
    if (tid < 128) red[tid] = s;
    __syncthreads();
    for (int st = 64; st; st >>= 1) { if (tid < st) red[tid] = fmaxf(red[tid], red[tid + st]); __syncthreads(); }
    float m = red[0];
    __syncthreads();
    float p = 0.f;
    if (tid < 128) { p = expf(s - m); parr[tid] = p; red[tid] = p; }
    __syncthreads();
    for (int st = 64; st; st >>= 1) { if (tid < st) red[tid] += red[tid + st]; __syncthreads(); }
    float ssum = red[0];
    int clV = tid & 15, rg = tid >> 4;
    const float* vb = cv + (size_t)(b * HH + h) * TENC * 64;
    float vx = 0, vy = 0, vz = 0, vw = 0;
#pragma unroll
    for (int it = 0; it < 8; ++it) {
        int i = rg * 8 + it;
        size_t jj = (size_t)(c * 128 + i);
        float4 v4 = *(const float4*)(vb + jj * 64 + clV * 4);
        float pw = parr[i];
        vx += pw * v4.x; vy += pw * v4.y; vz += pw * v4.z; vw += pw * v4.w;
    }
    pvred[rg][clV*4+0] = vx; pvred[rg][clV*4+1] = vy; pvred[rg][clV*4+2] = vz; pvred[rg][clV*4+3] = vw;
    __syncthreads();
    float* st_ = stats + (size_t)((b * HH + h) * 4 + c) * 66;
    if (tid == 0) { st_[0] = m; st_[1] = ssum; }
    if (tid < 64) {
        float pv = 0.f;
#pragma unroll
        for (int rgi = 0; rgi < 16; ++rgi) pv += pvred[rgi][tid];
        st_[2 + tid] = pv;
    }
}

// ---------------- generic GEMV, 64-col tiles ----------------
// grid=(N/64, R), block=256 (16 row-subgroups x 16 col-lanes of float4).
// ACT 0: fused residual+LN preload (K must be DD); 1: relu(abias+sum pin); 2: attention merge
template <int ACT>
__global__ __launch_bounds__(256) void gemv64(
    const float* __restrict__ W, int ldw, int K, int N,
    const float* __restrict__ xold, const float* __restrict__ rbias,
    const float* __restrict__ pin, int np,
    const float* __restrict__ lw, const float* __restrict__ lb,
    float* __restrict__ xnew,
    const float* __restrict__ abias,
    const float* __restrict__ stats, int nc,
    float* __restrict__ outp) {
    int cc = blockIdx.x, rc = blockIdx.y, R = gridDim.y, tid = threadIdx.x;
    int rows = K / R, row0 = rc * rows;
    __shared__ float vbuf[BB][DD];
    __shared__ float red[16][BB][64];
    float* vb = &vbuf[0][0];
    if (ACT == 0) {
        ln_preload(xold, rbias, pin, np, lw, lb, xnew, (xnew != nullptr) && cc == 0 && rc == 0, vbuf);
    } else {
        for (int i = tid; i < BB * rows; i += 256) {
            int b = i / rows, r = i % rows;
            float v;
            if (ACT == 1) {
                v = abias[row0 + r];
                for (int j = 0; j < np; ++j) v += pin[(size_t)(j * BB + b) * K + row0 + r];
                v = fmaxf(v, 0.0f);
            } else {
                int gr = row0 + r, hh = gr >> 6, dh = gr & 63;
                const float* st = stats + (size_t)(b * HH + hh) * nc * 66;
                float M = st[0];
                for (int cI = 1; cI < nc; ++cI) M = fmaxf(M, st[cI * 66]);
                float den = 0.f, num = 0.f;
                for (int cI = 0; cI < nc; ++cI) {
                    float e = expf(st[cI * 66] - M);
                    den += e * st[cI * 66 + 1];
                    num += e * st[cI * 66 + 2 + dh];
                }
                v = num / den;
            }
            vb[i] = v;   // flat [b*rows + r]
        }
    }
    __syncthreads();
    int cl = tid & 15, sg = tid >> 4;
    int colb = cc * 64;
    float4 a0 = {0,0,0,0}, a1 = {0,0,0,0}, a2 = {0,0,0,0}, a3 = {0,0,0,0};
    const float* Wp = W + (size_t)row0 * ldw + colb + cl * 4;
    int iters = rows >> 4;
#pragma unroll 4
    for (int it = 0; it < iters; ++it) {
        int r = sg + it * 16;
        float4 w4 = *(const float4*)(Wp + (size_t)r * ldw);
        if (ACT == 0) {
            int ai = row0 + r;
            fma4(a0, vbuf[0][ai], w4); fma4(a1, vbuf[1][ai], w4);
            fma4(a2, vbuf[2][ai], w4); fma4(a3, vbuf[3][ai], w4);
        } else {
            fma4(a0, vb[r], w4);             fma4(a1, vb[rows + r], w4);
            fma4(a2, vb[2 * rows + r], w4);  fma4(a3, vb[3 * rows + r], w4);
        }
    }
    int cq = cl * 4;
    red[sg][0][cq+0]=a0.x; red[sg][0][cq+1]=a0.y; red[sg][0][cq+2]=a0.z; red[sg][0][cq+3]=a0.w;
    red[sg][1][cq+0]=a1.x; red[sg][1][cq+1]=a1.y; red[sg][1][cq+2]=a1.z; red[sg][1][cq+3]=a1.w;
    red[sg][2][cq+0]=a2.x; red[sg][2][cq+1]=a2.y; red[sg][2][cq+2]=a2.z; red[sg][2][cq+3]=a2.w;
    red[sg][3][cq+0]=a3.x; red[sg][3][cq+1]=a3.y; red[sg][3][cq+2]=a3.z; red[sg][3][cq+3]=a3.w;
    __syncthreads();
    int b = tid >> 6, c = tid & 63;
    int col = colb + c;
    if (col < N) {
        float v = 0.f;
#pragma unroll
        for (int g = 0; g < 16; ++g) v += red[g][b][c];
        outp[(size_t)(rc * BB + b) * N + col] = v;
    }
}

__global__ __launch_bounds__(256) void proj_fin(
    const float* __restrict__ part, const float* __restrict__ pb, float* __restrict__ out) {
    int c = blockIdx.x * 256 + threadIdx.x;
    if (c < VV) {
        for (int b = 0; b < BB; ++b) {
            float v = pb[c];
            for (int rc = 0; rc < 4; ++rc) v += part[(size_t)(rc * BB + b) * VV + c];
            out[LG_OFF + (size_t)b * VV + c] = v;
        }
    }
    if (blockIdx.x == 0 && threadIdx.x == 0) out[KV_IDX] = (float)(HIST + 1);
}

// ---------------- host ----------------
extern "C" void kernel_launch(void* const* d_in, const int* in_sizes, int n_in,
                              void* d_out, int out_size, void* d_ws, size_t ws_size,
                              hipStream_t stream) {
    const float* kc    = (const float*)d_in[0];
    const float* vc    = (const float*)d_in[1];
    const float* ck    = (const float*)d_in[2];
    const float* cv    = (const float*)d_in[3];
    const int*   ids   = (const int*)d_in[4];
    const float* mflag = (const float*)d_in[7];
    const float* emb   = (const float*)d_in[8];
    const float* pe    = (const float*)d_in[9];
    const float* snw   = (const float*)d_in[10];
    const float* snb   = (const float*)d_in[11];
    const float* wq    = (const float*)d_in[12];
    const float* bq    = (const float*)d_in[13];
    const float* wk    = (const float*)d_in[14];
    const float* wv    = (const float*)d_in[15];
    const float* bv    = (const float*)d_in[16];
    const float* fcw   = (const float*)d_in[17];
    const float* fcb   = (const float*)d_in[18];
    const float* cnw   = (const float*)d_in[19];
    const float* cnb   = (const float*)d_in[20];
    const float* cwq   = (const float*)d_in[21];
    const float* cbq   = (const float*)d_in[22];
    const float* cfcw  = (const float*)d_in[23];
    const float* cfcb  = (const float*)d_in[24];
    const float* mnw   = (const float*)d_in[25];
    const float* mnb   = (const float*)d_in[26];
    const float* w1    = (const float*)d_in[27];
    const float* b1    = (const float*)d_in[28];
    const float* w2    = (const float*)d_in[29];
    const float* b2    = (const float*)d_in[30];
    const float* lnow  = (const float*)d_in[31];
    const float* lnob  = (const float*)d_in[32];
    const float* projw = (const float*)d_in[33];
    const float* projb = (const float*)d_in[34];

    float* out = (float*)d_out;
    float* ws  = (float*)d_ws;

    float* xA     = ws;                // 5120
    float* xB     = ws + 5120;         // 5120
    float* qkvp   = ws + 10240;        // 61440
    float* selfS  = ws + 71680;        // 4*20*8*66 = 42240
    float* crossS = ws + 113920;       // 4*20*4*66 = 21120
    float* fcP    = ws + 135040;       // 8*4*1280 = 40960
    float* cfcP   = ws + 176000;       // 40960
    float* f1P    = ws + 216960;       // 4*4*5120 = 81920
    float* ff2P   = ws + 298880;       // 16*4*1280 = 81920
    float* projP  = ws + 380800;       // 4*4*8000 = 128000

    float* nk = out + NK_OFF;
    float* nv = out + NV_OFF;

    embed_kernel<<<20, 256, 0, stream>>>(emb, pe, ids, xA);
    float* xo = xA;
    float* xn2 = xB;

    for (int l = 0; l < NLAYER; ++l) {
        const float* kc_l  = kc + (size_t)l * BB * HH * DHD * HIST;
        const float* vc_l  = vc + (size_t)l * BB * HH * HIST * DHD;
        const float* ck_l  = ck + (size_t)l * BB * HH * DHD * TENC;
        const float* cv_l  = cv + (size_t)l * BB * HH * TENC * DHD;
        float* nk_l = nk + (size_t)l * BB * HH * DHD * KVLEN;
        float* nv_l = nv + (size_t)l * BB * HH * KVLEN * DHD;
        const float* wq_l   = wq + (size_t)l * HH * DD * DHD;
        const float* wk_l   = wk + (size_t)l * HH * DD * DHD;
        const float* wv_l   = wv + (size_t)l * HH * DD * DHD;
        const float* cwq_l  = cwq + (size_t)l * HH * DD * DHD;
        const float* bq_l   = bq + (size_t)l * HH * DHD;
        const float* bv_l   = bv + (size_t)l * HH * DHD;
        const float* cbq_l  = cbq + (size_t)l * HH * DHD;
        const float* fcw_l  = fcw + (size_t)l * HH * DHD * DD;
        const float* cfcw_l = cfcw + (size_t)l * HH * DHD * DD;
        const float* fcb_l  = fcb + (size_t)l * DD;
        const float* cfcb_l = cfcb + (size_t)l * DD;
        const float* w1_l   = w1 + (size_t)l * DD * DFFN;
        const float* b1_l   = b1 + (size_t)l * DFFN;
        const float* w2_l   = w2 + (size_t)l * DFFN * DD;
        const float* b2_l   = b2 + (size_t)l * DD;

        // self-attn QKV (LN fused; residual from prev layer's FFN partials)
        const float* qrb  = (l == 0) ? nullptr : b2 + (size_t)(l - 1) * DD;
        const float* qpin = (l == 0) ? nullptr : ff2P;
        int          qnp  = (l == 0) ? 0 : 16;
        qkv64<<<dim3(HH, 12), 256, 0, stream>>>(wq_l, wk_l, wv_l, xo, qrb, qpin, qnp,
                                                snw + l * DD, snb + l * DD, xn2, qkvp);
        { float* t = xo; xo = xn2; xn2 = t; }

        attn_self_A<<<dim3(HH, BB, 8), 256, 0, stream>>>(kc_l, vc_l, qkvp, bq_l, bv_l, mflag,
                                                         nk_l, nv_l, selfS);
        gemv64<2><<<dim3(20, 8), 256, 0, stream>>>(fcw_l, DD, DD, DD,
            nullptr, nullptr, nullptr, 0, nullptr, nullptr, nullptr, nullptr, selfS, 8, fcP);

        // cross-attn Q (LN fused; residual = x + fcb + fc partials)
        qkv64<<<dim3(HH, 4), 256, 0, stream>>>(cwq_l, cwq_l, cwq_l, xo, fcb_l, fcP, 8,
                                               cnw + l * DD, cnb + l * DD, xn2, qkvp);
        { float* t = xo; xo = xn2; xn2 = t; }

        attn_cross_A<<<dim3(HH, BB, 4), 256, 0, stream>>>(ck_l, cv_l, qkvp, cbq_l, crossS);
        gemv64<2><<<dim3(20, 8), 256, 0, stream>>>(cfcw_l, DD, DD, DD,
            nullptr, nullptr, nullptr, 0, nullptr, nullptr, nullptr, nullptr, crossS, 4, cfcP);

        // FFN1 (LN fused; residual = x + cfcb + cfc partials)
        gemv64<0><<<dim3(80, 4), 256, 0, stream>>>(w1_l, DFFN, DD, DFFN,
            xo, cfcb_l, cfcP, 8, mnw + l * DD, mnb + l * DD, xn2,
            nullptr, nullptr, 0, f1P);
        { float* t = xo; xo = xn2; xn2 = t; }

        // FFN2 (relu merge of FFN1 partials)
        gemv64<1><<<dim3(20, 16), 256, 0, stream>>>(w2_l, DD, DFFN, DD,
            nullptr, nullptr, f1P, 4, nullptr, nullptr, nullptr, b1_l, nullptr, 0, ff2P);
    }

    // final projection (LN with lnow fused; residual = x + b2[15] + ffn2 partials)
    gemv64<0><<<dim3(125, 4), 256, 0, stream>>>(projw, VV, DD, VV,
        xo, b2 + (size_t)(NLAYER - 1) * DD, ff2P, 16, lnow, lnob, nullptr,
        nullptr, nullptr, 0, projP);
    proj_fin<<<32, 256, 0, stream>>>(projP, projb, out);
}